// Round 2
// baseline (221.908 us; speedup 1.0000x reference)
//
#include <hip/hip_runtime.h>

#define L_COORD 5.0f
#define L_NOOBJ 0.5f

#define CELLS_PER_BLOCK 256
#define BLOCK 256
#define FLOATS_PER_BLOCK (CELLS_PER_BLOCK * 30)   // 7680 floats = 30 KB

__device__ __forceinline__ float iou_one(float cx, float cy, float w, float h,
                                         float tx, float ty, float tw, float th) {
    float ax1 = cx - w * 0.5f, ay1 = cy - h * 0.5f;
    float ax2 = cx + w * 0.5f, ay2 = cy + h * 0.5f;
    float bx1 = tx - tw * 0.5f, by1 = ty - th * 0.5f;
    float bx2 = tx + tw * 0.5f, by2 = ty + th * 0.5f;
    float iw = fmaxf(fminf(ax2, bx2) - fmaxf(ax1, bx1), 0.0f);
    float ih = fmaxf(fminf(ay2, by2) - fmaxf(ay1, by1), 0.0f);
    float inter = iw * ih;
    float uni = w * h + tw * th - inter;
    return inter / fmaxf(uni, 1e-10f);
}

__global__ __launch_bounds__(BLOCK) void yolo_loss_partial(
    const float* __restrict__ pred, const float* __restrict__ target,
    float* __restrict__ acc, int ncells)
{
    __shared__ float smp[FLOATS_PER_BLOCK];
    __shared__ float smt[FLOATS_PER_BLOCK];

    const int block0 = blockIdx.x * CELLS_PER_BLOCK;          // first cell
    const int nc  = min(CELLS_PER_BLOCK, ncells - block0);    // cells this block
    const int nfl = nc * 30;                                  // floats this block
    const int nv4 = nfl >> 2;                                 // whole float4s

    // ---- coalesced staging: global float4 -> LDS ----
    const size_t fbase = (size_t)block0 * 30;
    const float4* p4 = reinterpret_cast<const float4*>(pred + fbase);
    const float4* t4 = reinterpret_cast<const float4*>(target + fbase);
    float4* smp4 = reinterpret_cast<float4*>(smp);
    float4* smt4 = reinterpret_cast<float4*>(smt);

    for (int i = threadIdx.x; i < nv4; i += BLOCK) {
        smp4[i] = p4[i];
        smt4[i] = t4[i];
    }
    // scalar tail (only possible in a partial last block)
    for (int i = (nv4 << 2) + threadIdx.x; i < nfl; i += BLOCK) {
        smp[i] = pred[fbase + i];
        smt[i] = target[fbase + i];
    }
    __syncthreads();

    float loc = 0.0f, cobj = 0.0f, cnoobj = 0.0f, clsn = 0.0f, nobj = 0.0f;

    if ((int)threadIdx.x < nc) {
        const float2* p2 = reinterpret_cast<const float2*>(&smp[threadIdx.x * 30]);
        const float2* t2 = reinterpret_cast<const float2*>(&smt[threadIdx.x * 30]);

        float p[30], t[30];
#pragma unroll
        for (int k = 0; k < 15; ++k) {
            float2 v = p2[k];
            p[2 * k] = v.x; p[2 * k + 1] = v.y;
        }
#pragma unroll
        for (int k = 0; k < 15; ++k) {
            float2 v = t2[k];
            t[2 * k] = v.x; t[2 * k + 1] = v.y;
        }

        float objf = (t[4] == 1.0f) ? 1.0f : 0.0f;
        float noobjf = 1.0f - objf;

        float iou0 = iou_one(p[0], p[1], p[2], p[3], t[0], t[1], t[2], t[3]);
        float iou1 = iou_one(p[5], p[6], p[7], p[8], t[0], t[1], t[2], t[3]);

        bool b0 = iou0 > iou1;
        float wx  = b0 ? p[0] : p[5];
        float wy  = b0 ? p[1] : p[6];
        float ww  = b0 ? p[2] : p[7];
        float whh = b0 ? p[3] : p[8];
        float wc  = b0 ? p[4] : p[9];
        float wiou = fmaxf(iou0, iou1);

        float dx = wx - t[0], dy = wy - t[1];
        float xy = dx * dx + dy * dy;
        float dw = sqrtf(ww) - sqrtf(t[2]);
        float dh = sqrtf(whh) - sqrtf(t[3]);
        float wh = dw * dw + dh * dh;
        loc += (xy + wh) * objf;

        float dc = wc - wiou;
        cobj += dc * dc * objf;

        // class CE: log_softmax over p[10..30), pick logit at argmax(target[10..30))
        float m = p[10];
#pragma unroll
        for (int k = 11; k < 30; ++k) m = fmaxf(m, p[k]);
        float s = 0.0f;
#pragma unroll
        for (int k = 10; k < 30; ++k) s += __expf(p[k] - m);

        float tm = t[10];
        float psel = p[10];
#pragma unroll
        for (int k = 11; k < 30; ++k) {
            bool gt = t[k] > tm;               // first-max wins (strict >)
            tm = gt ? t[k] : tm;
            psel = gt ? p[k] : psel;
        }
        float ce = (m + __logf(s)) - psel;
        clsn += ce * objf;
        nobj += objf;

        float d4 = p[4] - t[4], d9 = p[9] - t[9];
        cnoobj += (d4 * d4 + d9 * d9) * noobjf;
    }

    // ---- 64-lane wave reduction ----
#pragma unroll
    for (int off = 32; off > 0; off >>= 1) {
        loc    += __shfl_down(loc, off);
        cobj   += __shfl_down(cobj, off);
        cnoobj += __shfl_down(cnoobj, off);
        clsn   += __shfl_down(clsn, off);
        nobj   += __shfl_down(nobj, off);
    }

    __shared__ float sm[4][5];
    int lane = threadIdx.x & 63;
    int wid = threadIdx.x >> 6;
    if (lane == 0) {
        sm[wid][0] = loc; sm[wid][1] = cobj; sm[wid][2] = cnoobj;
        sm[wid][3] = clsn; sm[wid][4] = nobj;
    }
    __syncthreads();
    if (threadIdx.x == 0) {
        float a0 = 0.f, a1 = 0.f, a2 = 0.f, a3 = 0.f, a4 = 0.f;
#pragma unroll
        for (int w = 0; w < 4; ++w) {
            a0 += sm[w][0]; a1 += sm[w][1]; a2 += sm[w][2];
            a3 += sm[w][3]; a4 += sm[w][4];
        }
        atomicAdd(&acc[0], a0);
        atomicAdd(&acc[1], a1);
        atomicAdd(&acc[2], a2);
        atomicAdd(&acc[3], a3);
        atomicAdd(&acc[4], a4);
    }
}

__global__ void yolo_finalize(const float* __restrict__ acc,
                              float* __restrict__ out, float invB)
{
    float loc = acc[0], cobj = acc[1], cnoobj = acc[2], clsum = acc[3], nobj = acc[4];
    float n = fmaxf(nobj, 1.0f);
    float cls = clsum / n;
    float total = (L_COORD * loc + cobj + L_NOOBJ * cnoobj + cls) * invB;
    out[0] = total;
    out[1] = loc;
    out[2] = cobj;
    out[3] = cnoobj;
    out[4] = cls;
}

extern "C" void kernel_launch(void* const* d_in, const int* in_sizes, int n_in,
                              void* d_out, int out_size, void* d_ws, size_t ws_size,
                              hipStream_t stream) {
    const float* pred = (const float*)d_in[0];
    const float* target = (const float*)d_in[1];
    float* out = (float*)d_out;
    float* acc = (float*)d_ws;

    int ncells = in_sizes[0] / 30;          // B*S*S
    int B = ncells / 49;                    // S = 7

    hipMemsetAsync(acc, 0, 5 * sizeof(float), stream);

    int blocks = (ncells + CELLS_PER_BLOCK - 1) / CELLS_PER_BLOCK;
    yolo_loss_partial<<<blocks, BLOCK, 0, stream>>>(pred, target, acc, ncells);
    yolo_finalize<<<1, 1, 0, stream>>>(acc, out, 1.0f / (float)B);
}

// Round 3
// 40.209 us; speedup vs baseline: 5.5188x; 5.5188x over previous
//
#include <hip/hip_runtime.h>
#include <stdint.h>

#define L_COORD 5.0f
#define L_NOOBJ 0.5f

#define BLOCK 256
#define CPB   256                         // cells per chunk (= threads per block)
#define CHUNK_FLOATS (CPB * 30)           // 7680 floats = 30720 B per tensor
#define KB_PER_TENSOR 30                  // 30 x 1KiB DMA chunks per tensor

__device__ __forceinline__ float iou_one(float cx, float cy, float w, float h,
                                         float tx, float ty, float tw, float th) {
    float ax1 = cx - w * 0.5f, ay1 = cy - h * 0.5f;
    float ax2 = cx + w * 0.5f, ay2 = cy + h * 0.5f;
    float bx1 = tx - tw * 0.5f, by1 = ty - th * 0.5f;
    float bx2 = tx + tw * 0.5f, by2 = ty + th * 0.5f;
    float iw = fmaxf(fminf(ax2, bx2) - fmaxf(ax1, bx1), 0.0f);
    float ih = fmaxf(fminf(ay2, by2) - fmaxf(ay1, by1), 0.0f);
    float inter = iw * ih;
    float uni = w * h + tw * th - inter;
    return inter / fmaxf(uni, 1e-10f);
}

__global__ __launch_bounds__(BLOCK) void yolo_loss_partial(
    const float* __restrict__ pred, const float* __restrict__ target,
    float* __restrict__ partial,          // SoA: partial[comp * gridDim.x + bid]
    int nchunks)
{
    __shared__ float smp[CHUNK_FLOATS];
    __shared__ float smt[CHUNK_FLOATS];

    const int wid  = threadIdx.x >> 6;
    const int lane = threadIdx.x & 63;

    float loc = 0.0f, cobj = 0.0f, cnoobj = 0.0f, clsn = 0.0f, nobj = 0.0f;

    for (int chunk = blockIdx.x; chunk < nchunks; chunk += gridDim.x) {
        const size_t fbase = (size_t)chunk * CHUNK_FLOATS;

        // ---- async global -> LDS staging, 1 KiB per instruction ----
        // wave w handles 1KiB-subchunks c = w, w+4, ... ; lane l covers bytes l*16..l*16+15
        for (int c = wid; c < KB_PER_TENSOR; c += 4) {
            const float* gp = pred   + fbase + c * 256 + lane * 4;
            const float* gt = target + fbase + c * 256 + lane * 4;
            __builtin_amdgcn_global_load_lds(
                (const __attribute__((address_space(1))) void*)gp,
                (__attribute__((address_space(3))) void*)&smp[c * 256], 16, 0, 0);
            __builtin_amdgcn_global_load_lds(
                (const __attribute__((address_space(1))) void*)gt,
                (__attribute__((address_space(3))) void*)&smt[c * 256], 16, 0, 0);
        }
        asm volatile("s_waitcnt vmcnt(0)" ::: "memory");
        __syncthreads();

        // ---- per-cell math, one cell per thread, all compile-time indices ----
        {
            const float2* p2 = reinterpret_cast<const float2*>(&smp[threadIdx.x * 30]);
            const float2* t2 = reinterpret_cast<const float2*>(&smt[threadIdx.x * 30]);

            float p[30], t[30];
#pragma unroll
            for (int k = 0; k < 15; ++k) {
                float2 v = p2[k];
                p[2 * k] = v.x; p[2 * k + 1] = v.y;
            }
#pragma unroll
            for (int k = 0; k < 15; ++k) {
                float2 v = t2[k];
                t[2 * k] = v.x; t[2 * k + 1] = v.y;
            }

            float objf = (t[4] == 1.0f) ? 1.0f : 0.0f;
            float noobjf = 1.0f - objf;

            float iou0 = iou_one(p[0], p[1], p[2], p[3], t[0], t[1], t[2], t[3]);
            float iou1 = iou_one(p[5], p[6], p[7], p[8], t[0], t[1], t[2], t[3]);

            bool b0 = iou0 > iou1;
            float wx  = b0 ? p[0] : p[5];
            float wy  = b0 ? p[1] : p[6];
            float ww  = b0 ? p[2] : p[7];
            float whh = b0 ? p[3] : p[8];
            float wc  = b0 ? p[4] : p[9];
            float wiou = fmaxf(iou0, iou1);

            float dx = wx - t[0], dy = wy - t[1];
            float xy = dx * dx + dy * dy;
            float dw = sqrtf(ww) - sqrtf(t[2]);
            float dh = sqrtf(whh) - sqrtf(t[3]);
            float wh = dw * dw + dh * dh;
            loc += (xy + wh) * objf;

            float dc = wc - wiou;
            cobj += dc * dc * objf;

            float m = p[10];
#pragma unroll
            for (int k = 11; k < 30; ++k) m = fmaxf(m, p[k]);
            float s = 0.0f;
#pragma unroll
            for (int k = 10; k < 30; ++k) s += __expf(p[k] - m);

            float tm = t[10];
            float psel = p[10];
#pragma unroll
            for (int k = 11; k < 30; ++k) {
                bool gt = t[k] > tm;           // first-max wins (strict >)
                tm = gt ? t[k] : tm;
                psel = gt ? p[k] : psel;
            }
            float ce = (m + __logf(s)) - psel;
            clsn += ce * objf;
            nobj += objf;

            float d4 = p[4] - t[4], d9 = p[9] - t[9];
            cnoobj += (d4 * d4 + d9 * d9) * noobjf;
        }

        __syncthreads();   // LDS reuse barrier before next chunk's staging
    }

    // ---- block reduction: wave shuffle tree then cross-wave LDS ----
#pragma unroll
    for (int off = 32; off > 0; off >>= 1) {
        loc    += __shfl_down(loc, off);
        cobj   += __shfl_down(cobj, off);
        cnoobj += __shfl_down(cnoobj, off);
        clsn   += __shfl_down(clsn, off);
        nobj   += __shfl_down(nobj, off);
    }

    __shared__ float sm[4][5];
    if (lane == 0) {
        sm[wid][0] = loc; sm[wid][1] = cobj; sm[wid][2] = cnoobj;
        sm[wid][3] = clsn; sm[wid][4] = nobj;
    }
    __syncthreads();
    if (threadIdx.x == 0) {
        float a0 = 0.f, a1 = 0.f, a2 = 0.f, a3 = 0.f, a4 = 0.f;
#pragma unroll
        for (int w = 0; w < 4; ++w) {
            a0 += sm[w][0]; a1 += sm[w][1]; a2 += sm[w][2];
            a3 += sm[w][3]; a4 += sm[w][4];
        }
        int g = gridDim.x, b = blockIdx.x;
        partial[0 * g + b] = a0;
        partial[1 * g + b] = a1;
        partial[2 * g + b] = a2;
        partial[3 * g + b] = a3;
        partial[4 * g + b] = a4;
    }
}

__global__ __launch_bounds__(256) void yolo_reduce(
    const float* __restrict__ partial, int n, float* __restrict__ out, float invB)
{
    float v0 = 0.f, v1 = 0.f, v2 = 0.f, v3 = 0.f, v4 = 0.f;
    for (int i = threadIdx.x; i < n; i += 256) {
        v0 += partial[0 * n + i];
        v1 += partial[1 * n + i];
        v2 += partial[2 * n + i];
        v3 += partial[3 * n + i];
        v4 += partial[4 * n + i];
    }
#pragma unroll
    for (int off = 32; off > 0; off >>= 1) {
        v0 += __shfl_down(v0, off);
        v1 += __shfl_down(v1, off);
        v2 += __shfl_down(v2, off);
        v3 += __shfl_down(v3, off);
        v4 += __shfl_down(v4, off);
    }
    __shared__ float sm[4][5];
    int lane = threadIdx.x & 63;
    int wid = threadIdx.x >> 6;
    if (lane == 0) {
        sm[wid][0] = v0; sm[wid][1] = v1; sm[wid][2] = v2;
        sm[wid][3] = v3; sm[wid][4] = v4;
    }
    __syncthreads();
    if (threadIdx.x == 0) {
        float loc = 0.f, cobj = 0.f, cnoobj = 0.f, clsum = 0.f, nobj = 0.f;
#pragma unroll
        for (int w = 0; w < 4; ++w) {
            loc += sm[w][0]; cobj += sm[w][1]; cnoobj += sm[w][2];
            clsum += sm[w][3]; nobj += sm[w][4];
        }
        float nn = fmaxf(nobj, 1.0f);
        float cls = clsum / nn;
        float total = (L_COORD * loc + cobj + L_NOOBJ * cnoobj + cls) * invB;
        out[0] = total;
        out[1] = loc;
        out[2] = cobj;
        out[3] = cnoobj;
        out[4] = cls;
    }
}

extern "C" void kernel_launch(void* const* d_in, const int* in_sizes, int n_in,
                              void* d_out, int out_size, void* d_ws, size_t ws_size,
                              hipStream_t stream) {
    const float* pred = (const float*)d_in[0];
    const float* target = (const float*)d_in[1];
    float* out = (float*)d_out;
    float* partial = (float*)d_ws;

    int ncells = in_sizes[0] / 30;            // B*S*S = 802816 (divisible by 256)
    int B = ncells / 49;                      // S = 7
    int nchunks = ncells / CPB;               // 3136 exactly

    int blocks = nchunks;
    int maxb = (int)(ws_size / (5 * sizeof(float)));
    if (blocks > maxb) blocks = maxb;         // grid-stride covers the rest
    if (blocks < 1) blocks = 1;

    yolo_loss_partial<<<blocks, BLOCK, 0, stream>>>(pred, target, partial, nchunks);
    yolo_reduce<<<1, 256, 0, stream>>>(partial, blocks, out, 1.0f / (float)B);
}